// Round 1
// baseline (362.129 us; speedup 1.0000x reference)
//
#include <hip/hip_runtime.h>

#define WSZ 11
#define PAD 5
#define TILE 32
#define IN_TILE (TILE + WSZ - 1)  // 42

// --- Gaussian weights computed per-thread (11 expf, negligible; matches f32 ref) ---
__device__ __forceinline__ void gauss_weights(float g[WSZ]) {
    float s = 0.f;
#pragma unroll
    for (int i = 0; i < WSZ; ++i) {
        float x = (float)(i - PAD);
        g[i] = expf(-(x * x) / (2.f * 1.5f * 1.5f));
        s += g[i];
    }
    float inv = 1.f / s;
#pragma unroll
    for (int i = 0; i < WSZ; ++i) g[i] *= inv;
}

__global__ __launch_bounds__(256) void init_accum_kernel(double* accum) {
    if (threadIdx.x < 4) accum[threadIdx.x] = 0.0;
}

// One 32x32 output tile per block. Separable conv via LDS, zero padding at borders.
__global__ __launch_bounds__(256) void ssim_scale_kernel(
    const float* __restrict__ img1, const float* __restrict__ img2,
    int H, int W, double* __restrict__ accum, int slot)
{
    __shared__ float s1[IN_TILE][IN_TILE];
    __shared__ float s2[IN_TILE][IN_TILE];
    __shared__ float h1[IN_TILE][TILE];
    __shared__ float h2[IN_TILE][TILE];
    __shared__ float h11[IN_TILE][TILE];
    __shared__ float h22[IN_TILE][TILE];
    __shared__ float h12[IN_TILE][TILE];
    __shared__ float wsum[4];

    const int tid = threadIdx.x;
    const int ox = blockIdx.x * TILE;
    const int oy = blockIdx.y * TILE;
    const size_t base = (size_t)blockIdx.z * H * W;

    float g[WSZ];
    gauss_weights(g);

    // Stage 42x42 tiles of both images (zero padding outside).
    for (int idx = tid; idx < IN_TILE * IN_TILE; idx += 256) {
        int r = idx / IN_TILE, c = idx % IN_TILE;
        int y = oy + r - PAD, x = ox + c - PAD;
        float v1 = 0.f, v2 = 0.f;
        if (y >= 0 && y < H && x >= 0 && x < W) {
            size_t off = base + (size_t)y * W + x;
            v1 = img1[off];
            v2 = img2[off];
        }
        s1[r][c] = v1;
        s2[r][c] = v2;
    }
    __syncthreads();

    // Horizontal 11-tap pass: 42 rows x 32 output cols, 5 quantities.
    for (int idx = tid; idx < IN_TILE * TILE; idx += 256) {
        int r = idx / TILE, c = idx % TILE;
        float a1 = 0.f, a2 = 0.f, a11 = 0.f, a22 = 0.f, a12 = 0.f;
#pragma unroll
        for (int k = 0; k < WSZ; ++k) {
            float w = g[k];
            float v1 = s1[r][c + k];
            float v2 = s2[r][c + k];
            a1  += w * v1;
            a2  += w * v2;
            a11 += w * v1 * v1;
            a22 += w * v2 * v2;
            a12 += w * v1 * v2;
        }
        h1[r][c] = a1; h2[r][c] = a2;
        h11[r][c] = a11; h22[r][c] = a22; h12[r][c] = a12;
    }
    __syncthreads();

    // Vertical 11-tap pass + SSIM map + partial sum.
    const float C1 = 0.01f * 0.01f;
    const float C2 = 0.03f * 0.03f;
    float local = 0.f;
    for (int idx = tid; idx < TILE * TILE; idx += 256) {
        int r = idx / TILE, c = idx % TILE;
        float mu1 = 0.f, mu2 = 0.f, m11 = 0.f, m22 = 0.f, m12 = 0.f;
#pragma unroll
        for (int k = 0; k < WSZ; ++k) {
            float w = g[k];
            mu1 += w * h1[r + k][c];
            mu2 += w * h2[r + k][c];
            m11 += w * h11[r + k][c];
            m22 += w * h22[r + k][c];
            m12 += w * h12[r + k][c];
        }
        float mu1_sq = mu1 * mu1;
        float mu2_sq = mu2 * mu2;
        float mu12   = mu1 * mu2;
        float sig1   = m11 - mu1_sq;
        float sig2   = m22 - mu2_sq;
        float sig12  = m12 - mu12;
        float num = (2.f * mu12 + C1) * (2.f * sig12 + C2);
        float den = (mu1_sq + mu2_sq + C1) * (sig1 + sig2 + C2);
        local += num / den;
    }

    // Block reduction: wave64 shuffle, then cross-wave via LDS, one double atomic.
#pragma unroll
    for (int off = 32; off > 0; off >>= 1) local += __shfl_down(local, off);
    if ((tid & 63) == 0) wsum[tid >> 6] = local;
    __syncthreads();
    if (tid == 0) {
        float bs = wsum[0] + wsum[1] + wsum[2] + wsum[3];
        atomicAdd(&accum[slot], (double)bs);
    }
}

// 2x2 avg pool on both images.
__global__ __launch_bounds__(256) void pool_kernel(
    const float* __restrict__ in1, const float* __restrict__ in2,
    float* __restrict__ out1, float* __restrict__ out2,
    int Ho, int Wo, int total)
{
    int idx = blockIdx.x * 256 + threadIdx.x;
    if (idx >= total) return;
    int x = idx % Wo;
    int t = idx / Wo;
    int y = t % Ho;
    int z = t / Ho;
    int Wi = Wo * 2;
    size_t ib = (((size_t)z * (Ho * 2) + 2 * y) * Wi) + 2 * x;
    out1[idx] = 0.25f * (in1[ib] + in1[ib + 1] + in1[ib + Wi] + in1[ib + Wi + 1]);
    out2[idx] = 0.25f * (in2[ib] + in2[ib + 1] + in2[ib + Wi] + in2[ib + Wi + 1]);
}

__global__ void finalize_kernel(const double* __restrict__ accum, float* __restrict__ out,
                                double c0, double c1, double c2, double c3)
{
    const double w[4] = {0.0448, 0.2856, 0.3001, 0.2363};
    const double cnt[4] = {c0, c1, c2, c3};
    double loss = 0.0;
#pragma unroll
    for (int s = 0; s < 4; ++s) loss += w[s] * (1.0 - accum[s] / cnt[s]);
    out[0] = (float)loss;
}

extern "C" void kernel_launch(void* const* d_in, const int* in_sizes, int n_in,
                              void* d_out, int out_size, void* d_ws, size_t ws_size,
                              hipStream_t stream) {
    const float* img1 = (const float*)d_in[0];
    const float* img2 = (const float*)d_in[1];
    float* out = (float*)d_out;

    const int H0 = 512, W0 = 512;
    const int NC = in_sizes[0] / (H0 * W0);  // 16*3 = 48

    // Workspace layout
    double* accum = (double*)d_ws;  // 4 doubles
    float* buf = (float*)((char*)d_ws + 64);
    const size_t n1 = (size_t)NC * 256 * 256;
    const size_t n2 = (size_t)NC * 128 * 128;
    const size_t n3 = (size_t)NC * 64 * 64;
    float* a1 = buf;            // img1 scale1
    float* b1 = a1 + n1;        // img2 scale1
    float* a2 = b1 + n1;
    float* b2 = a2 + n2;
    float* a3 = b2 + n2;
    float* b3 = a3 + n3;

    init_accum_kernel<<<1, 64, 0, stream>>>(accum);

    // Scale 0 (512x512)
    {
        dim3 grid(W0 / TILE, H0 / TILE, NC);
        ssim_scale_kernel<<<grid, 256, 0, stream>>>(img1, img2, H0, W0, accum, 0);
    }
    // Pool to scale 1 (256x256)
    {
        int total = (int)n1;
        pool_kernel<<<(total + 255) / 256, 256, 0, stream>>>(img1, img2, a1, b1, 256, 256, total);
        dim3 grid(256 / TILE, 256 / TILE, NC);
        ssim_scale_kernel<<<grid, 256, 0, stream>>>(a1, b1, 256, 256, accum, 1);
    }
    // Pool to scale 2 (128x128)
    {
        int total = (int)n2;
        pool_kernel<<<(total + 255) / 256, 256, 0, stream>>>(a1, b1, a2, b2, 128, 128, total);
        dim3 grid(128 / TILE, 128 / TILE, NC);
        ssim_scale_kernel<<<grid, 256, 0, stream>>>(a2, b2, 128, 128, accum, 2);
    }
    // Pool to scale 3 (64x64)
    {
        int total = (int)n3;
        pool_kernel<<<(total + 255) / 256, 256, 0, stream>>>(a2, b2, a3, b3, 64, 64, total);
        dim3 grid(64 / TILE, 64 / TILE, NC);
        ssim_scale_kernel<<<grid, 256, 0, stream>>>(a3, b3, 64, 64, accum, 3);
    }

    double c0 = (double)NC * 512.0 * 512.0;
    double c1 = (double)NC * 256.0 * 256.0;
    double c2 = (double)NC * 128.0 * 128.0;
    double c3 = (double)NC * 64.0 * 64.0;
    finalize_kernel<<<1, 1, 0, stream>>>(accum, out, c0, c1, c2, c3);
}

// Round 2
// 330.626 us; speedup vs baseline: 1.0953x; 1.0953x over previous
//
#include <hip/hip_runtime.h>

typedef float f2 __attribute__((ext_vector_type(2)));
typedef float f4 __attribute__((ext_vector_type(4)));

#define WSZ 11
#define PAD 5
#define TILE 32
#define IN_TILE 42              // TILE + WSZ - 1
#define S_STRIDE 44             // float2 elems per staged row (16B-aligned rows)
#define HA_STRIDE 45            // float4 elems per column of hA (odd -> conflict-free b128)
#define HB_STRIDE 52            // floats per column of hB (13*4 -> uniform quad-groups, 16B-aligned)

__device__ __forceinline__ void gauss_weights(float g[WSZ]) {
    float s = 0.f;
#pragma unroll
    for (int i = 0; i < WSZ; ++i) {
        float x = (float)(i - PAD);
        g[i] = expf(-(x * x) / (2.f * 1.5f * 1.5f));
        s += g[i];
    }
    float inv = 1.f / s;
#pragma unroll
    for (int i = 0; i < WSZ; ++i) g[i] *= inv;
}

__global__ __launch_bounds__(64) void init_accum_kernel(double* accum) {
    if (threadIdx.x < 4) accum[threadIdx.x] = 0.0;
}

// One 32x32 output tile per block, 256 threads.
// Phase 1: stage 42x42 (v1,v2) pairs into LDS (zero-padded borders).
// Phase 2: horizontal 11-tap conv, 4 outputs/item, pk-fp32, results stored transposed.
// Phase 3: vertical 11-tap conv down contiguous columns + SSIM epilogue + reduce.
// Phase 3b: fused 2x2 avg-pool of the staged tile -> interleaved float2 output.
__global__ __launch_bounds__(256, 3) void ssim_scale_kernel(
    const float* __restrict__ img1, const float* __restrict__ img2,
    const f2* __restrict__ pair,           // interleaved input (scales > 0), else nullptr
    int H, int W, double* __restrict__ accum, int slot,
    f2* __restrict__ pout)                 // pooled interleaved output (nullptr on last scale)
{
    __shared__ f2 s2d[IN_TILE * S_STRIDE];     // 14784 B
    __shared__ f4 hA[TILE * HA_STRIDE];        // 23040 B  (mu1, mu2, x12, e11)
    __shared__ float hB[TILE * HB_STRIDE];     // 6656 B   (e22)
    __shared__ float wsum[4];

    const int tid = threadIdx.x;
    const int ox = blockIdx.x * TILE;
    const int oy = blockIdx.y * TILE;
    const int z = blockIdx.z;

    float g[WSZ];
    gauss_weights(g);

    // ---- Phase 1: staging ----
    {
        const size_t base = (size_t)z * H * W;
        for (int idx = tid; idx < IN_TILE * IN_TILE; idx += 256) {
            int r = idx / IN_TILE, c = idx - r * IN_TILE;
            int y = oy + r - PAD, x = ox + c - PAD;
            f2 v = {0.f, 0.f};
            if (y >= 0 && y < H && x >= 0 && x < W) {
                size_t off = base + (size_t)y * W + x;
                if (pair) v = pair[off];
                else      v = (f2){img1[off], img2[off]};
            }
            s2d[r * S_STRIDE + c] = v;
        }
    }
    __syncthreads();

    // ---- Phase 2: horizontal conv (42 rows x 8 col-quads = 336 items) ----
    for (int idx = tid; idx < IN_TILE * 8; idx += 256) {
        int r = idx >> 3;
        int j0 = (idx & 7) * 4;
        const f4* sp = (const f4*)&s2d[r * S_STRIDE + j0];   // 16B-aligned
        f2 p[16];
#pragma unroll
        for (int n = 0; n < 8; ++n) {
            f4 t = sp[n];
            p[2 * n]     = (f2){t.x, t.y};
            p[2 * n + 1] = (f2){t.z, t.w};
        }
        f2 q[14];
        float xx[14];
#pragma unroll
        for (int n = 0; n < 14; ++n) {
            q[n]  = p[n] * p[n];            // pk: (v1^2, v2^2)
            xx[n] = p[n].x * p[n].y;        // v1*v2
        }
#pragma unroll
        for (int o = 0; o < 4; ++o) {
            f2 mu = {0.f, 0.f};
            f2 sq = {0.f, 0.f};
            float xv = 0.f;
#pragma unroll
            for (int k = 0; k < WSZ; ++k) {
                float w = g[k];
                mu += p[o + k] * w;         // v_pk_fma_f32
                sq += q[o + k] * w;         // v_pk_fma_f32
                xv += xx[o + k] * w;
            }
            int col = j0 + o;
            hA[col * HA_STRIDE + r] = (f4){mu.x, mu.y, xv, sq.x};
            hB[col * HB_STRIDE + r] = sq.y;
        }
    }
    __syncthreads();

    // ---- Phase 3: vertical conv + SSIM (32 cols x 8 row-quads = 256 items) ----
    const float C1 = 0.01f * 0.01f;
    const float C2 = 0.03f * 0.03f;
    float local = 0.f;
    {
        const int c = tid & 31;
        const int r0 = (tid >> 5) * 4;
        f4 A[14];
        const f4* ap = &hA[c * HA_STRIDE + r0];
#pragma unroll
        for (int n = 0; n < 14; ++n) A[n] = ap[n];
        const f4* bp = (const f4*)&hB[c * HB_STRIDE + r0];   // 16B-aligned (52%4==0, r0%4==0)
        float Bv[16];
#pragma unroll
        for (int n = 0; n < 4; ++n) {
            f4 t = bp[n];
            Bv[4 * n] = t.x; Bv[4 * n + 1] = t.y; Bv[4 * n + 2] = t.z; Bv[4 * n + 3] = t.w;
        }
#pragma unroll
        for (int o = 0; o < 4; ++o) {
            f4 acc = {0.f, 0.f, 0.f, 0.f};
            float e22 = 0.f;
#pragma unroll
            for (int k = 0; k < WSZ; ++k) {
                float w = g[k];
                acc += A[o + k] * w;        // 2x v_pk_fma_f32
                e22 += Bv[o + k] * w;
            }
            float mu1 = acc.x, mu2 = acc.y, x12 = acc.z, e11 = acc.w;
            float mu11 = mu1 * mu1, mu22 = mu2 * mu2, mu12 = mu1 * mu2;
            float sig1 = e11 - mu11;
            float sig2 = e22 - mu22;
            float sig12 = x12 - mu12;
            float num = (2.f * mu12 + C1) * (2.f * sig12 + C2);
            float den = (mu11 + mu22 + C1) * (sig1 + sig2 + C2);
            local += num * __builtin_amdgcn_rcpf(den);
        }
    }

    // ---- Phase 3b: fused 2x2 avg-pool (uses staged s2d, still valid) ----
    if (pout) {
        int px = tid & 15, py = tid >> 4;          // 16x16 pooled outputs per tile
        int rr = PAD + 2 * py, cc = PAD + 2 * px;
        f2 a = s2d[rr * S_STRIDE + cc];
        f2 b = s2d[rr * S_STRIDE + cc + 1];
        f2 c2 = s2d[(rr + 1) * S_STRIDE + cc];
        f2 d = s2d[(rr + 1) * S_STRIDE + cc + 1];
        f2 m = (a + b + c2 + d) * 0.25f;
        int Wo = W >> 1;
        size_t obase = (size_t)z * (H >> 1) * Wo;
        pout[obase + (size_t)((oy >> 1) + py) * Wo + ((ox >> 1) + px)] = m;
    }

    // ---- Reduction: wave shuffle -> LDS -> one double atomic per block ----
#pragma unroll
    for (int off = 32; off > 0; off >>= 1) local += __shfl_down(local, off);
    if ((tid & 63) == 0) wsum[tid >> 6] = local;
    __syncthreads();
    if (tid == 0) {
        float bs = wsum[0] + wsum[1] + wsum[2] + wsum[3];
        atomicAdd(&accum[slot], (double)bs);
    }
}

__global__ void finalize_kernel(const double* __restrict__ accum, float* __restrict__ out,
                                double c0, double c1, double c2, double c3)
{
    const double w[4] = {0.0448, 0.2856, 0.3001, 0.2363};
    const double cnt[4] = {c0, c1, c2, c3};
    double loss = 0.0;
#pragma unroll
    for (int s = 0; s < 4; ++s) loss += w[s] * (1.0 - accum[s] / cnt[s]);
    out[0] = (float)loss;
}

extern "C" void kernel_launch(void* const* d_in, const int* in_sizes, int n_in,
                              void* d_out, int out_size, void* d_ws, size_t ws_size,
                              hipStream_t stream) {
    const float* img1 = (const float*)d_in[0];
    const float* img2 = (const float*)d_in[1];
    float* out = (float*)d_out;

    const int H0 = 512, W0 = 512;
    const int NC = in_sizes[0] / (H0 * W0);  // 16*3 = 48

    // Workspace: 4 doubles accum + interleaved (v1,v2) pair buffers for scales 1..3
    double* accum = (double*)d_ws;
    f2* p1 = (f2*)((char*)d_ws + 64);                       // NC*256*256 pairs
    f2* p2 = p1 + (size_t)NC * 256 * 256;                   // NC*128*128
    f2* p3 = p2 + (size_t)NC * 128 * 128;                   // NC*64*64

    init_accum_kernel<<<1, 64, 0, stream>>>(accum);

    {   // Scale 0 (512) -> writes pooled p1 (256)
        dim3 grid(W0 / TILE, H0 / TILE, NC);
        ssim_scale_kernel<<<grid, 256, 0, stream>>>(img1, img2, nullptr, H0, W0, accum, 0, p1);
    }
    {   // Scale 1 (256) -> p2
        dim3 grid(8, 8, NC);
        ssim_scale_kernel<<<grid, 256, 0, stream>>>(nullptr, nullptr, p1, 256, 256, accum, 1, p2);
    }
    {   // Scale 2 (128) -> p3
        dim3 grid(4, 4, NC);
        ssim_scale_kernel<<<grid, 256, 0, stream>>>(nullptr, nullptr, p2, 128, 128, accum, 2, p3);
    }
    {   // Scale 3 (64), no pooled output
        dim3 grid(2, 2, NC);
        ssim_scale_kernel<<<grid, 256, 0, stream>>>(nullptr, nullptr, p3, 64, 64, accum, 3, nullptr);
    }

    double c0 = (double)NC * 512.0 * 512.0;
    double c1 = (double)NC * 256.0 * 256.0;
    double c2 = (double)NC * 128.0 * 128.0;
    double c3 = (double)NC * 64.0 * 64.0;
    finalize_kernel<<<1, 1, 0, stream>>>(accum, out, c0, c1, c2, c3);
}